// Round 7
// baseline (435.412 us; speedup 1.0000x reference)
//
#include <hip/hip_runtime.h>
#include <hip/hip_bf16.h>
#include <stdint.h>

// FusedLinearCrossEntropyLoss on MI355X (gfx950)
// loss = mean_i( logsumexp_j(x_i . w_j + b_j) - (x_i . w_t(i) + b_t(i)) )
//
// R7: no-LDS fragment-direct GEMM (R6) with hipBLASLt-shape blocking:
//     wave tile 128x128 (4x4 of 32x32x64 fp8 MFMAs, 256 acc regs), block
//     256x256, 1 wave/SIMD (__launch_bounds__(256,1), 512-reg budget).
//     Loads/MFMA 1.5 -> 1.0; MFMA pipe becomes dominant; ILP hides L1/L2.
//
// Fragment chunk layout (from cast_swz_k): chunk c = R*16 + g covers rows
// R*32..+31, k g*64..+63. data[c*2048 + h*1024 + lane*16 + j] =
//   M[R*32 + (lane&31)][g*64 + (lane>>5)*32 + h*16 + j]

typedef float f16v __attribute__((ext_vector_type(16)));
typedef int v8i __attribute__((ext_vector_type(8)));

__device__ __forceinline__ unsigned pk_fp8(float4 v) {
  int w = 0;
  w = __builtin_amdgcn_cvt_pk_fp8_f32(v.x, v.y, w, false);  // bytes 0,1
  w = __builtin_amdgcn_cvt_pk_fp8_f32(v.z, v.w, w, true);   // bytes 2,3
  return (unsigned)w;
}

// fp32 [N x 1024] -> fp8 fragment-swizzled chunks. One thread = 16 out bytes.
__global__ __launch_bounds__(256) void cast_swz_k(const float* __restrict__ in,
                                                  uint4* __restrict__ out,
                                                  long n16) {
  long t = (long)blockIdx.x * blockDim.x + threadIdx.x;
  long stride = (long)gridDim.x * blockDim.x;
  for (; t < n16; t += stride) {
    long o = t * 16;
    int c = (int)(o >> 11);
    int rem = (int)(o & 2047);
    int h = rem >> 10;
    int lam = (rem >> 4) & 63;
    int row = (c >> 4) * 32 + (lam & 31);
    int k = (c & 15) * 64 + (lam >> 5) * 32 + h * 16;
    const float4* src = (const float4*)(in + (long)row * 1024 + k);
    uint4 oo;
    oo.x = pk_fp8(src[0]); oo.y = pk_fp8(src[1]);
    oo.z = pk_fp8(src[2]); oo.w = pk_fp8(src[3]);
    out[t] = oo;
  }
}

// One block per row: x_y[row] = x[row] . W[safe_t] + bias[safe_t]  (fp32, exact)
__global__ __launch_bounds__(256) void xy_k(const float* __restrict__ x,
                                            const float* __restrict__ w,
                                            const float* __restrict__ bias,
                                            const int* __restrict__ tgt,
                                            float* __restrict__ xy, int H, int V) {
  int row = blockIdx.x;
  int t = tgt[row];
  int st = min(max(t, 0), V - 1);
  const float4* xr = (const float4*)(x + (long)row * H);
  const float4* wr = (const float4*)(w + (long)st * H);
  float s = 0.f;
  int n4 = H >> 2;
  for (int i = threadIdx.x; i < n4; i += 256) {
    float4 a = xr[i], b = wr[i];
    s += a.x * b.x + a.y * b.y + a.z * b.z + a.w * b.w;
  }
  for (int off = 32; off; off >>= 1) s += __shfl_down(s, off, 64);
  __shared__ float sm[4];
  if ((threadIdx.x & 63) == 0) sm[threadIdx.x >> 6] = s;
  __syncthreads();
  if (threadIdx.x == 0) xy[row] = sm[0] + sm[1] + sm[2] + sm[3] + bias[st];
}

// 256x256 block tile, 4 waves in 2x2; each wave 128x128 via 4x4 of 32x32x64.
// All operands loaded straight from global fragment chunks (no LDS staging).
// Epilogue: partials[bn][row] = sum_cols exp(logit + bias).
__global__ __launch_bounds__(256, 1)
void gemm_sumexp(const char* __restrict__ Xf, const char* __restrict__ Wf,
                 const float* __restrict__ bias, float* __restrict__ partials,
                 int H, int BT) {
  __shared__ float rowsum[2][256];

  const int tid = threadIdx.x;
  const int w = tid >> 6, lane = tid & 63;
  const int wr = w >> 1, wc = w & 1;
  const int l32 = lane & 31, kh = lane >> 5;
  const int m0 = blockIdx.x * 256, n0 = blockIdx.y * 256;

  f16v acc[4][4];
#pragma unroll
  for (int mi = 0; mi < 4; mi++)
#pragma unroll
    for (int ni = 0; ni < 4; ni++)
#pragma unroll
      for (int r = 0; r < 16; r++) acc[mi][ni][r] = 0.f;

  const int Rb = blockIdx.x * 8 + wr * 4;   // A 32-row chunk-row base
  const int Nb = blockIdx.y * 8 + wc * 4;   // B 32-row chunk-row base

  const char* pa[4];
  const char* pb[4];
#pragma unroll
  for (int mi = 0; mi < 4; mi++)
    pa[mi] = Xf + ((long)(Rb + mi) * 16) * 2048 + lane * 16;
#pragma unroll
  for (int ni = 0; ni < 4; ni++)
    pb[ni] = Wf + ((long)(Nb + ni) * 16) * 2048 + lane * 16;

  const int nG = H >> 6;  // 16 k-groups of 64
#pragma unroll 2
  for (int g = 0; g < nG; g++) {
    v8i a[4], b[4];
#pragma unroll
    for (int mi = 0; mi < 4; mi++) {
      int4 lo = *(const int4*)(pa[mi]);
      int4 hi = *(const int4*)(pa[mi] + 1024);
      v8i t;
      t[0] = lo.x; t[1] = lo.y; t[2] = lo.z; t[3] = lo.w;
      t[4] = hi.x; t[5] = hi.y; t[6] = hi.z; t[7] = hi.w;
      a[mi] = t;
      pa[mi] += 2048;
    }
#pragma unroll
    for (int ni = 0; ni < 4; ni++) {
      int4 lo = *(const int4*)(pb[ni]);
      int4 hi = *(const int4*)(pb[ni] + 1024);
      v8i t;
      t[0] = lo.x; t[1] = lo.y; t[2] = lo.z; t[3] = lo.w;
      t[4] = hi.x; t[5] = hi.y; t[6] = hi.z; t[7] = hi.w;
      b[ni] = t;
      pb[ni] += 2048;
    }
#pragma unroll
    for (int mi = 0; mi < 4; mi++)
#pragma unroll
      for (int ni = 0; ni < 4; ni++)
        acc[mi][ni] = __builtin_amdgcn_mfma_scale_f32_32x32x64_f8f6f4(
            a[mi], b[ni], acc[mi][ni], 0 /*A=fp8*/, 0 /*B=fp8*/,
            0, 127 /*scale_a = 1.0*/, 0, 127 /*scale_b = 1.0*/);
  }

  // ---- epilogue: per-row sum of exp(logit + bias) ----
  // C/D 32x32 layout: col = lane&31, row = (reg&3) + 8*(reg>>2) + 4*(lane>>5)
  float bv[4];
#pragma unroll
  for (int ni = 0; ni < 4; ni++) bv[ni] = bias[n0 + wc * 128 + ni * 32 + l32];

#pragma unroll
  for (int mi = 0; mi < 4; mi++) {
    float p[16];
#pragma unroll
    for (int r = 0; r < 16; r++) p[r] = 0.f;
#pragma unroll
    for (int ni = 0; ni < 4; ni++)
#pragma unroll
      for (int r = 0; r < 16; r++) p[r] += __expf(acc[mi][ni][r] + bv[ni]);
    // reduce across the 32 columns (lanes within each 32-group)
#pragma unroll
    for (int off = 1; off < 32; off <<= 1)
#pragma unroll
      for (int r = 0; r < 16; r++) p[r] += __shfl_xor(p[r], off, 32);
    if (l32 == 0) {
#pragma unroll
      for (int r = 0; r < 16; r++)
        rowsum[wc][wr * 128 + mi * 32 + (r & 3) + 8 * (r >> 2) + 4 * kh] = p[r];
    }
  }
  __syncthreads();
  partials[(long)blockIdx.y * BT + m0 + tid] = rowsum[0][tid] + rowsum[1][tid];
}

// per-row: lse - x_y ; block partial sums
__global__ __launch_bounds__(256)
void row_reduce(const float* __restrict__ partials, const float* __restrict__ xy,
                const int* __restrict__ tgt, float* __restrict__ bsum,
                float* __restrict__ bcnt, int BT, int nCB) {
  int row = blockIdx.x * 256 + threadIdx.x;
  float S = 0.f;
  for (int b = 0; b < nCB; b++) S += partials[(long)b * BT + row];
  int t = tgt[row];
  bool valid = (t != -100);
  float pr = valid ? (logf(S) - xy[row]) : 0.f;
  float c = valid ? 1.f : 0.f;
  for (int off = 32; off; off >>= 1) {
    pr += __shfl_down(pr, off, 64);
    c += __shfl_down(c, off, 64);
  }
  __shared__ float sp[4], sc[4];
  if ((threadIdx.x & 63) == 0) {
    sp[threadIdx.x >> 6] = pr;
    sc[threadIdx.x >> 6] = c;
  }
  __syncthreads();
  if (threadIdx.x == 0) {
    bsum[blockIdx.x] = sp[0] + sp[1] + sp[2] + sp[3];
    bcnt[blockIdx.x] = sc[0] + sc[1] + sc[2] + sc[3];
  }
}

__global__ void finalize(const float* __restrict__ bsum, const float* __restrict__ bcnt,
                         float* __restrict__ out, int nb) {
  float s = 0.f, c = 0.f;
  for (int i = threadIdx.x; i < nb; i += 64) { s += bsum[i]; c += bcnt[i]; }
  for (int off = 32; off; off >>= 1) {
    s += __shfl_down(s, off, 64);
    c += __shfl_down(c, off, 64);
  }
  if (threadIdx.x == 0) out[0] = s / c;
}

extern "C" void kernel_launch(void* const* d_in, const int* in_sizes, int n_in,
                              void* d_out, int out_size, void* d_ws, size_t ws_size,
                              hipStream_t stream) {
  const float* x = (const float*)d_in[0];
  const int* tgt = (const int*)d_in[1];
  const float* w = (const float*)d_in[2];
  const float* bias = (const float*)d_in[3];
  float* out = (float*)d_out;

  const int BT = in_sizes[1];            // 4096
  const int V = in_sizes[3];             // 32000
  const int H = in_sizes[0] / BT;        // 1024
  const int nCB = V / 256;               // 125 column blocks

  char* ws = (char*)d_ws;
  const long wb_bytes = (long)V * H;     // fp8: 1 B/elem
  const long xb_bytes = (long)BT * H;
  char* Wf = ws;
  char* Xf = ws + wb_bytes;
  float* partials = (float*)(ws + wb_bytes + xb_bytes);
  float* xy = partials + (long)nCB * BT;
  float* bsum = xy + BT;
  float* bcnt = bsum + (BT / 256);

  cast_swz_k<<<8192, 256, 0, stream>>>(w, (uint4*)Wf, (long)V * H / 16);
  cast_swz_k<<<1024, 256, 0, stream>>>(x, (uint4*)Xf, (long)BT * H / 16);
  xy_k<<<BT, 256, 0, stream>>>(x, w, bias, tgt, xy, H, V);
  // grid.x = row-blocks (fast-varying) so consecutive blocks share the W tile in L2
  dim3 grid(BT / 256, nCB);
  gemm_sumexp<<<grid, 256, 0, stream>>>(Xf, Wf, bias, partials, H, BT);
  row_reduce<<<BT / 256, 256, 0, stream>>>(partials, xy, tgt, bsum, bcnt, BT, nCB);
  finalize<<<1, 64, 0, stream>>>(bsum, bcnt, out, BT / 256);
}